// Round 5
// baseline (174.256 us; speedup 1.0000x reference)
//
#include <hip/hip_runtime.h>
#include <math.h>

#define B_ 2
#define L_ 2048
#define H_ 16
#define E_ 64
#define D_ 64
#define DM_ 512
#define DH_ 256

typedef __bf16 bf16_t;
typedef bf16_t bf16x8_t __attribute__((ext_vector_type(8)));
typedef float f32x4_t __attribute__((ext_vector_type(4)));

// pack two floats to bf16x2 (round-up-at-halfway; 2 add + 1 perm)
__device__ __forceinline__ unsigned bpack(float hi, float lo) {
    unsigned uh = __float_as_uint(hi) + 0x8000u;
    unsigned ul = __float_as_uint(lo) + 0x8000u;
    return __builtin_amdgcn_perm(uh, ul, 0x07060302u);
}

__device__ __forceinline__ bf16_t to_bf16(float f) {
    union { float f; unsigned u; } x; x.f = f;
    unsigned r = (x.u + 0x7fffu + ((x.u >> 16) & 1u)) >> 16;
    union { unsigned short s; bf16_t b; } y; y.s = (unsigned short)r;
    return y.b;
}

// ---------------- w1 [512 k][256 n] f32 -> w1t [256 n][512 k] bf16 ------------
__global__ __launch_bounds__(256) void transpose_w1_kernel(
        const float* __restrict__ w1, bf16_t* __restrict__ w1t) {
    const int n = blockIdx.x;
    const int t = threadIdx.x;
    #pragma unroll
    for (int u = 0; u < 2; ++u) {
        int k = t + u * 256;
        float v = w1[(size_t)k * DH_ + n];
        w1t[(size_t)n * DM_ + k] = to_bf16(v);
    }
}

// ---------------- MLP via MFMA, split-K: fused = relu(raw@w1+b1)@w2 + b2 -----
__global__ __launch_bounds__(512) void mlp_kernel(
        const float* __restrict__ raw, const bf16_t* __restrict__ w1t,
        const float* __restrict__ b1, const float* __restrict__ w2,
        const float* __restrict__ b2, float* __restrict__ fused) {
    __shared__ bf16_t Rs[16][520];
    __shared__ float pk[4][4][16][17];
    __shared__ float part[4][16];
    const int t = threadIdx.x;
    const int m0 = blockIdx.x * 16;
    #pragma unroll
    for (int u = 0; u < 4; ++u) {
        int idx = t + u * 512;
        int row = idx >> 7;
        int k = (idx & 127) << 2;
        f32x4_t v = *(const f32x4_t*)&raw[(size_t)(m0 + row) * DM_ + k];
        uint2 p;
        p.x = bpack(v[1], v[0]);
        p.y = bpack(v[3], v[2]);
        *(uint2*)&Rs[row][k] = p;
    }
    __syncthreads();
    const int wave = t >> 6;
    const int lane = t & 63;
    const int lrow = lane & 15;
    const int lgrp = lane >> 4;
    const int nq   = wave & 3;
    const int kh   = wave >> 2;
    const int n0w  = nq * 64;
    const int k0   = kh * 256;

    f32x4_t acc[4];
    #pragma unroll
    for (int nt = 0; nt < 4; ++nt) acc[nt] = (f32x4_t){0.f, 0.f, 0.f, 0.f};

    const bf16_t* wbase = w1t + (size_t)(n0w + lrow) * DM_ + k0 + lgrp * 8;
    #pragma unroll
    for (int s = 0; s < 8; ++s) {
        bf16x8_t a = *(const bf16x8_t*)&Rs[lrow][k0 + s * 32 + lgrp * 8];
        #pragma unroll
        for (int nt = 0; nt < 4; ++nt) {
            bf16x8_t b = *(const bf16x8_t*)(wbase + nt * 16 * DM_ + s * 32);
            acc[nt] = __builtin_amdgcn_mfma_f32_16x16x32_bf16(a, b, acc[nt], 0, 0, 0);
        }
    }
    if (kh == 1) {
        #pragma unroll
        for (int nt = 0; nt < 4; ++nt)
            #pragma unroll
            for (int r = 0; r < 4; ++r)
                pk[nq][nt][lgrp * 4 + r][lrow] = acc[nt][r];
    }
    __syncthreads();
    if (kh == 0) {
        float rowpart[4] = {0.f, 0.f, 0.f, 0.f};
        #pragma unroll
        for (int nt = 0; nt < 4; ++nt) {
            int n = n0w + nt * 16 + lrow;
            float b1v = b1[n];
            float w2v = w2[n];
            #pragma unroll
            for (int r = 0; r < 4; ++r) {
                float h = acc[nt][r] + pk[nq][nt][lgrp * 4 + r][lrow] + b1v;
                h = h > 0.f ? h : 0.f;
                rowpart[r] += h * w2v;
            }
        }
        #pragma unroll
        for (int r = 0; r < 4; ++r) {
            float v = rowpart[r];
            v += __shfl_xor(v, 1);
            v += __shfl_xor(v, 2);
            v += __shfl_xor(v, 4);
            v += __shfl_xor(v, 8);
            if (lrow == 0) part[nq][lgrp * 4 + r] = v;
        }
    }
    __syncthreads();
    if (t < 16)
        fused[m0 + t] = part[0][t] + part[1][t] + part[2][t] + part[3][t] + b2[0];
}

// ---------------- flash attention, balanced via s-range splitting -------------
// grid = 1536: wid = bid>>5 (0..47), bh = bid&31.
//   wid<32: split block, qt = 31-(wid>>1) in [16,31], chunk = wid&1
//   wid>=32: direct block, qt = 47-wid in [0,15]
struct TileRegs { f32x4_t k[4]; float v[16]; float m; };

__global__ __launch_bounds__(256) void attn_kernel(
        const float* __restrict__ Q, const float* __restrict__ K,
        const float* __restrict__ V, const float* __restrict__ fused,
        const float* __restrict__ alpha_trend, float* __restrict__ out,
        bf16_t* __restrict__ pO, float* __restrict__ prs) {
    __shared__ bf16_t Ks[64][72];             // [s][e], 144-B rows, b128-aligned
    __shared__ bf16_t Vt[64][70];             // [d][s], 140-B rows, 32-bank write spread
    __shared__ unsigned short Ps[4][16][68];  // per-wave P scratch
    __shared__ float moms[64];

    const int bid  = blockIdx.x;
    const int bh   = bid & 31;
    const int wid  = bid >> 5;
    int qt, sa, sb, chunk;
    bool split;
    if (wid < 32) {
        qt    = 31 - (wid >> 1);
        chunk = wid & 1;
        int half = (qt + 2) >> 1;            // ceil((qt+1)/2)
        sa = chunk ? half : 0;
        sb = chunk ? qt + 1 : half;
        split = true;
    } else {
        qt = 47 - wid;
        sa = 0; sb = qt + 1; chunk = 0;
        split = false;
    }
    const int h    = bh & 15;
    const int b    = bh >> 4;
    const int q0   = qt << 6;
    const int tid  = threadIdx.x;
    const int wave = tid >> 6;
    const int lane = tid & 63;
    const int lrow = lane & 15;
    const int lgrp = lane >> 4;

    const float c1      = 0.18033688f;        // 0.125 * log2(e)
    const float ascale2 = alpha_trend[h] * c1;
    const size_t bl     = (size_t)b * L_;
    const int qw0       = q0 + wave * 16;

    const float* Kb = K + (bl * H_ + h) * E_;
    const float* Vb = V + (bl * H_ + h) * D_;
    const float* fp = fused + bl;

    const int krow = tid >> 4;
    const int ke0  = (tid & 15) << 2;
    const int vd   = tid & 63;
    const int vsb  = tid >> 6;

    // Q fragments, prescaled by c1
    bf16x8_t a_lo, a_hi;
    {
        const float* qp = Q + ((bl + qw0 + lrow) * H_ + h) * E_ + lgrp * 8;
        f32x4_t v0 = *(const f32x4_t*)(qp);
        f32x4_t v1 = *(const f32x4_t*)(qp + 4);
        f32x4_t v2 = *(const f32x4_t*)(qp + 32);
        f32x4_t v3 = *(const f32x4_t*)(qp + 36);
        #pragma unroll
        for (int k = 0; k < 4; ++k) {
            a_lo[k]     = to_bf16(v0[k] * c1);
            a_lo[4 + k] = to_bf16(v1[k] * c1);
            a_hi[k]     = to_bf16(v2[k] * c1);
            a_hi[4 + k] = to_bf16(v3[k] * c1);
        }
    }
    float mq[4];
    #pragma unroll
    for (int r = 0; r < 4; ++r) {
        int l = qw0 + lgrp * 4 + r;
        mq[r] = (l == 0) ? 0.f : fp[l] - fp[l - 1];
    }

    f32x4_t Oacc[4];
    #pragma unroll
    for (int c = 0; c < 4; ++c) Oacc[c] = (f32x4_t){0.f, 0.f, 0.f, 0.f};
    float rowsum[4] = {0.f, 0.f, 0.f, 0.f};

    TileRegs tr;
    #define LOAD_TILE(st_) do {                                                   \
        const int s0_ = (st_) << 6;                                               \
        _Pragma("unroll")                                                         \
        for (int u = 0; u < 4; ++u)                                               \
            tr.k[u] = *(const f32x4_t*)&Kb[(s0_ + krow + u * 16) * (H_ * E_) + ke0]; \
        _Pragma("unroll")                                                         \
        for (int j = 0; j < 16; ++j)                                              \
            tr.v[j] = Vb[(s0_ + vsb * 16 + j) * (H_ * D_) + vd];                  \
        if (tid < 64) {                                                           \
            int l_ = s0_ + tid;                                                   \
            tr.m = (l_ == 0) ? 0.f : fp[l_] - fp[l_ - 1];                         \
        }                                                                         \
    } while (0)

    LOAD_TILE(sa);

    for (int st = sa; st < sb; ++st) {
        __syncthreads();   // previous tile's LDS readers done
        // stage K: b64 writes, 16-B aligned rows
        #pragma unroll
        for (int u = 0; u < 4; ++u) {
            uint2 p;
            p.x = bpack(tr.k[u][1], tr.k[u][0]);
            p.y = bpack(tr.k[u][3], tr.k[u][2]);
            *(uint2*)&Ks[krow + u * 16][ke0] = p;
        }
        // stage V^T: b32 writes (rows only 4-B aligned), all-bank spread
        #pragma unroll
        for (int u = 0; u < 4; ++u) {
            unsigned* vp = (unsigned*)&Vt[vd][vsb * 16 + u * 4];
            vp[0] = bpack(tr.v[u * 4 + 1], tr.v[u * 4 + 0]);
            vp[1] = bpack(tr.v[u * 4 + 3], tr.v[u * 4 + 2]);
        }
        if (tid < 64) moms[tid] = tr.m;
        __syncthreads();   // stage visible

        if (st + 1 < sb) LOAD_TILE(st + 1);

        // S = Q K^T (log2 domain via prescale)
        f32x4_t Sacc[4];
        #pragma unroll
        for (int c = 0; c < 4; ++c) Sacc[c] = (f32x4_t){0.f, 0.f, 0.f, 0.f};
        #pragma unroll
        for (int c = 0; c < 4; ++c) {
            bf16x8_t b_lo = *(const bf16x8_t*)&Ks[c * 16 + lrow][lgrp * 8];
            bf16x8_t b_hi = *(const bf16x8_t*)&Ks[c * 16 + lrow][32 + lgrp * 8];
            Sacc[c] = __builtin_amdgcn_mfma_f32_16x16x32_bf16(a_lo, b_lo, Sacc[c], 0, 0, 0);
            Sacc[c] = __builtin_amdgcn_mfma_f32_16x16x32_bf16(a_hi, b_hi, Sacc[c], 0, 0, 0);
        }

        // P = exp2(S - ascale2*|dm|)
        float rowe[4][4];
        #pragma unroll
        for (int c = 0; c < 4; ++c) {
            float ms = moms[c * 16 + lrow];
            #pragma unroll
            for (int r = 0; r < 4; ++r) {
                float arg = Sacc[c][r] - ascale2 * fabsf(mq[r] - ms);
                rowe[c][r] = __builtin_amdgcn_exp2f(arg);
            }
        }
        if (st == qt) {
            const int s0 = st << 6;
            #pragma unroll
            for (int c = 0; c < 4; ++c) {
                int sg = s0 + c * 16 + lrow;
                #pragma unroll
                for (int r = 0; r < 4; ++r)
                    if (sg > qw0 + lgrp * 4 + r) rowe[c][r] = 0.f;
            }
        }
        // P -> wave-private LDS: truncated bf16 via d16_hi store (0 pack VALU)
        unsigned short* Psw = &Ps[wave][0][0];
        #pragma unroll
        for (int c = 0; c < 4; ++c) {
            #pragma unroll
            for (int r = 0; r < 4; ++r) {
                Psw[(lgrp * 4 + r) * 68 + c * 16 + lrow] =
                    (unsigned short)(__float_as_uint(rowe[c][r]) >> 16);
                rowsum[r] += rowe[c][r];
            }
        }

        // O += P V
        #pragma unroll
        for (int hh = 0; hh < 2; ++hh) {
            union { uint2 u2[2]; bf16x8_t v; } ab;
            ab.u2[0] = *(const uint2*)&Psw[lrow * 68 + hh * 32 + lgrp * 8];
            ab.u2[1] = *(const uint2*)&Psw[lrow * 68 + hh * 32 + lgrp * 8 + 4];
            #pragma unroll
            for (int c2 = 0; c2 < 4; ++c2) {
                union { unsigned u[4]; bf16x8_t v; } bb;
                const unsigned* vp = (const unsigned*)&Vt[c2 * 16 + lrow][hh * 32 + lgrp * 8];
                bb.u[0] = vp[0]; bb.u[1] = vp[1]; bb.u[2] = vp[2]; bb.u[3] = vp[3];
                Oacc[c2] = __builtin_amdgcn_mfma_f32_16x16x32_bf16(ab.v, bb.v, Oacc[c2], 0, 0, 0);
            }
        }
    }

    if (!split) {
        // direct: normalize and store
        #pragma unroll
        for (int r = 0; r < 4; ++r) {
            float rs = rowsum[r];
            rs += __shfl_xor(rs, 1);
            rs += __shfl_xor(rs, 2);
            rs += __shfl_xor(rs, 4);
            rs += __shfl_xor(rs, 8);
            float inv = 1.f / rs;
            size_t orow = ((bl + qw0 + lgrp * 4 + r) * H_ + h) * D_;
            #pragma unroll
            for (int c = 0; c < 4; ++c)
                out[orow + c * 16 + lrow] = Oacc[c][r] * inv;
        }
    } else {
        // partial: un-normalized bf16 O + f32 rowsums to workspace
        const int slot = (bh * 16 + (qt - 16)) * 2 + chunk;
        bf16_t* po = pO + (size_t)slot * 4096;
        float*  pr = prs + (size_t)slot * 64;
        #pragma unroll
        for (int r = 0; r < 4; ++r) {
            float rs = rowsum[r];
            rs += __shfl_xor(rs, 1);
            rs += __shfl_xor(rs, 2);
            rs += __shfl_xor(rs, 4);
            rs += __shfl_xor(rs, 8);
            int q = wave * 16 + lgrp * 4 + r;
            if (lrow == 0) pr[q] = rs;
            #pragma unroll
            for (int c = 0; c < 4; ++c)
                po[q * 64 + c * 16 + lrow] = to_bf16(Oacc[c][r]);
        }
    }
    #undef LOAD_TILE
}

// ---------------- merge partials for qt in [16,31] ----------------------------
// grid = 512: bh = bid&31, qt = 16 + (bid>>5). 256 threads.
__global__ __launch_bounds__(256) void merge_kernel(
        const bf16_t* __restrict__ pO, const float* __restrict__ prs,
        float* __restrict__ out) {
    const int bid = blockIdx.x;
    const int bh  = bid & 31;
    const int qt  = 16 + (bid >> 5);
    const int h   = bh & 15;
    const int b   = bh >> 4;
    const int t   = threadIdx.x;
    const int q   = t >> 2;
    const int d0  = (t & 3) << 4;

    const int slotA = (bh * 16 + (qt - 16)) * 2;
    const bf16_t* poA = pO + (size_t)slotA * 4096 + q * 64 + d0;
    const bf16_t* poB = poA + 4096;
    float rs = prs[slotA * 64 + q] + prs[(slotA + 1) * 64 + q];
    float inv = 1.f / rs;

    float* op = out + (((size_t)b * L_ + (qt << 6) + q) * H_ + h) * D_ + d0;
    #pragma unroll
    for (int i = 0; i < 16; i += 4) {
        f32x4_t o;
        #pragma unroll
        for (int k = 0; k < 4; ++k)
            o[k] = ((float)poA[i + k] + (float)poB[i + k]) * inv;
        *(f32x4_t*)&op[i] = o;
    }
}

extern "C" void kernel_launch(void* const* d_in, const int* in_sizes, int n_in,
                              void* d_out, int out_size, void* d_ws, size_t ws_size,
                              hipStream_t stream) {
    const float* Q     = (const float*)d_in[0];
    const float* K     = (const float*)d_in[1];
    const float* V     = (const float*)d_in[2];
    const float* raw   = (const float*)d_in[3];
    const float* w1    = (const float*)d_in[4];
    const float* b1    = (const float*)d_in[5];
    const float* w2    = (const float*)d_in[6];
    const float* b2    = (const float*)d_in[7];
    const float* alpha = (const float*)d_in[8];
    float* out = (float*)d_out;

    float* fused = (float*)d_ws;                        // 4096 f32
    bf16_t* w1t  = (bf16_t*)(fused + B_ * L_);          // 131072 bf16
    bf16_t* pO   = w1t + (size_t)DH_ * DM_;             // 1024*4096 bf16 (8 MB)
    float* prs   = (float*)(pO + (size_t)1024 * 4096);  // 1024*64 f32

    transpose_w1_kernel<<<DH_, 256, 0, stream>>>(w1, w1t);
    mlp_kernel<<<B_ * L_ / 16, 512, 0, stream>>>(raw, w1t, b1, w2, b2, fused);
    attn_kernel<<<1536, 256, 0, stream>>>(Q, K, V, fused, alpha, out, pO, prs);
    merge_kernel<<<512, 256, 0, stream>>>(pO, prs, out);
}

// Round 6
// 173.416 us; speedup vs baseline: 1.0048x; 1.0048x over previous
//
#include <hip/hip_runtime.h>
#include <math.h>

#define B_ 2
#define L_ 2048
#define H_ 16
#define E_ 64
#define D_ 64
#define DM_ 512
#define DH_ 256

typedef __bf16 bf16_t;
typedef bf16_t bf16x8_t __attribute__((ext_vector_type(8)));
typedef float f32x4_t __attribute__((ext_vector_type(4)));

__device__ __forceinline__ unsigned bpack(float hi, float lo) {
    unsigned uh = __float_as_uint(hi) + 0x8000u;
    unsigned ul = __float_as_uint(lo) + 0x8000u;
    return __builtin_amdgcn_perm(uh, ul, 0x07060302u);
}

__device__ __forceinline__ bf16_t to_bf16(float f) {
    union { float f; unsigned u; } x; x.f = f;
    unsigned r = (x.u + 0x7fffu + ((x.u >> 16) & 1u)) >> 16;
    union { unsigned short s; bf16_t b; } y; y.s = (unsigned short)r;
    return y.b;
}

// ------- w1 [512 k][256 n] f32 -> w1t [256 n][512 k] bf16, coalesced ---------
// grid 32: block = (k-tile 64) x (n-tile 64)
__global__ __launch_bounds__(256) void transpose_w1_kernel(
        const float* __restrict__ w1, bf16_t* __restrict__ w1t) {
    __shared__ float sT[64][65];
    const int t  = threadIdx.x;
    const int k0 = (blockIdx.x >> 2) * 64;
    const int n0 = (blockIdx.x & 3) * 64;
    const int nn = t & 63;
    #pragma unroll
    for (int u = 0; u < 16; ++u) {
        int k = (t >> 6) + u * 4;
        sT[k][nn] = w1[(size_t)(k0 + k) * DH_ + n0 + nn];
    }
    __syncthreads();
    const int nr = t >> 2;
    const int kc = (t & 3) * 16;
    unsigned pk0[8];
    #pragma unroll
    for (int j = 0; j < 8; ++j)
        pk0[j] = bpack(sT[kc + 2 * j + 1][nr], sT[kc + 2 * j][nr]);
    bf16_t* dst = w1t + (size_t)(n0 + nr) * DM_ + k0 + kc;
    ((uint2*)dst)[0] = make_uint2(pk0[0], pk0[1]);
    ((uint2*)dst)[1] = make_uint2(pk0[2], pk0[3]);
    ((uint2*)dst)[2] = make_uint2(pk0[4], pk0[5]);
    ((uint2*)dst)[3] = make_uint2(pk0[6], pk0[7]);
}

// ------- MLP: fused += partial(relu(raw@w1+b1)@w2) over n-half ---------------
// grid 512: block = (m-tile 16) x (n-half 128); 4 waves = (kh,nq). b2 cancels
// in the momentum diff, so fused is zero-init + atomic partial sums.
__global__ __launch_bounds__(256) void mlp_kernel(
        const float* __restrict__ raw, const bf16_t* __restrict__ w1t,
        const float* __restrict__ b1, const float* __restrict__ w2,
        float* __restrict__ fused) {
    __shared__ bf16_t Rs[16][520];
    __shared__ float pk[2][4][16][17];
    __shared__ float part[2][16];
    const int t  = threadIdx.x;
    const int m0 = (blockIdx.x >> 1) * 16;
    const int nh = blockIdx.x & 1;
    #pragma unroll
    for (int u = 0; u < 8; ++u) {
        int idx = t + u * 256;
        int row = idx >> 7;
        int k   = (idx & 127) << 2;
        f32x4_t v = *(const f32x4_t*)&raw[(size_t)(m0 + row) * DM_ + k];
        uint2 p;
        p.x = bpack(v[1], v[0]);
        p.y = bpack(v[3], v[2]);
        *(uint2*)&Rs[row][k] = p;
    }
    __syncthreads();
    const int wave = t >> 6;
    const int lane = t & 63;
    const int lrow = lane & 15;
    const int lgrp = lane >> 4;
    const int kh   = wave >> 1;
    const int nq   = wave & 1;
    const int n0w  = nh * 128 + nq * 64;
    const int k0   = kh * 256;

    f32x4_t acc[4];
    #pragma unroll
    for (int nt = 0; nt < 4; ++nt) acc[nt] = (f32x4_t){0.f, 0.f, 0.f, 0.f};

    const bf16_t* wbase = w1t + (size_t)(n0w + lrow) * DM_ + k0 + lgrp * 8;
    #pragma unroll
    for (int s = 0; s < 8; ++s) {
        bf16x8_t a = *(const bf16x8_t*)&Rs[lrow][k0 + s * 32 + lgrp * 8];
        #pragma unroll
        for (int nt = 0; nt < 4; ++nt) {
            bf16x8_t b = *(const bf16x8_t*)(wbase + nt * 16 * DM_ + s * 32);
            acc[nt] = __builtin_amdgcn_mfma_f32_16x16x32_bf16(a, b, acc[nt], 0, 0, 0);
        }
    }
    if (kh == 1) {
        #pragma unroll
        for (int nt = 0; nt < 4; ++nt)
            #pragma unroll
            for (int r = 0; r < 4; ++r)
                pk[nq][nt][lgrp * 4 + r][lrow] = acc[nt][r];
    }
    __syncthreads();
    if (kh == 0) {
        float rowpart[4] = {0.f, 0.f, 0.f, 0.f};
        #pragma unroll
        for (int nt = 0; nt < 4; ++nt) {
            int n = n0w + nt * 16 + lrow;
            float b1v = b1[n];
            float w2v = w2[n];
            #pragma unroll
            for (int r = 0; r < 4; ++r) {
                float hv = acc[nt][r] + pk[nq][nt][lgrp * 4 + r][lrow] + b1v;
                hv = hv > 0.f ? hv : 0.f;
                rowpart[r] += hv * w2v;
            }
        }
        #pragma unroll
        for (int r = 0; r < 4; ++r) {
            float v = rowpart[r];
            v += __shfl_xor(v, 1);
            v += __shfl_xor(v, 2);
            v += __shfl_xor(v, 4);
            v += __shfl_xor(v, 8);
            if (lrow == 0) part[nq][lgrp * 4 + r] = v;
        }
    }
    __syncthreads();
    if (t < 16)
        atomicAdd(&fused[m0 + t], part[0][t] + part[1][t]);
}

// ------- flash attention: 2 waves x 32 q-rows, 64q block, split-s balance ----
__global__ __launch_bounds__(128, 3) void attn_kernel(
        const float* __restrict__ Q, const float* __restrict__ K,
        const float* __restrict__ V, const float* __restrict__ fused,
        const float* __restrict__ alpha_trend, float* __restrict__ out,
        bf16_t* __restrict__ pO, float* __restrict__ prs) {
    __shared__ bf16_t Ks[64][72];             // [s][e], 144-B rows, b128 reads
    __shared__ bf16_t Vt[64][76];             // [d][s], 152-B rows, b64 ops (R4-best)
    __shared__ unsigned short Ps[2][32][68];  // per-wave P scratch
    __shared__ float moms[64];

    const int bid  = blockIdx.x;
    const int bh   = bid & 31;
    const int wid  = bid >> 5;
    int qt, sa, sb, chunk;
    bool split;
    if (wid < 32) {
        qt    = 31 - (wid >> 1);
        chunk = wid & 1;
        int half = (qt + 2) >> 1;
        sa = chunk ? half : 0;
        sb = chunk ? qt + 1 : half;
        split = true;
    } else {
        qt = 47 - wid;
        sa = 0; sb = qt + 1; chunk = 0;
        split = false;
    }
    const int h    = bh & 15;
    const int b    = bh >> 4;
    const int q0   = qt << 6;
    const int tid  = threadIdx.x;
    const int wave = tid >> 6;
    const int lane = tid & 63;
    const int lrow = lane & 15;
    const int lgrp = lane >> 4;

    const float c1      = 0.18033688f;        // 0.125 * log2(e)
    const float ascale2 = alpha_trend[h] * c1;
    const size_t bl     = (size_t)b * L_;
    const int qw0       = q0 + wave * 32;     // this wave's 32 q rows

    const float* Kb = K + (bl * H_ + h) * E_;
    const float* Vb = V + (bl * H_ + h) * D_;
    const float* fp = fused + bl;

    const int krow = tid >> 4;                // 0..7
    const int ke0  = (tid & 15) << 2;
    const int vd   = tid & 63;
    const int vsb  = tid >> 6;                // 0..1

    // Q fragments for 2 row-blocks, prescaled by c1
    bf16x8_t aq[2][2];
    #pragma unroll
    for (int mh = 0; mh < 2; ++mh) {
        const float* qp = Q + ((bl + qw0 + mh * 16 + lrow) * H_ + h) * E_ + lgrp * 8;
        f32x4_t v0 = *(const f32x4_t*)(qp);
        f32x4_t v1 = *(const f32x4_t*)(qp + 4);
        f32x4_t v2 = *(const f32x4_t*)(qp + 32);
        f32x4_t v3 = *(const f32x4_t*)(qp + 36);
        #pragma unroll
        for (int k = 0; k < 4; ++k) {
            aq[mh][0][k]     = to_bf16(v0[k] * c1);
            aq[mh][0][4 + k] = to_bf16(v1[k] * c1);
            aq[mh][1][k]     = to_bf16(v2[k] * c1);
            aq[mh][1][4 + k] = to_bf16(v3[k] * c1);
        }
    }
    float mq[2][4];
    #pragma unroll
    for (int mh = 0; mh < 2; ++mh)
        #pragma unroll
        for (int r = 0; r < 4; ++r) {
            int l = qw0 + mh * 16 + lgrp * 4 + r;
            mq[mh][r] = (l == 0) ? 0.f : fp[l] - fp[l - 1];
        }

    f32x4_t Oacc[2][4];
    #pragma unroll
    for (int mh = 0; mh < 2; ++mh)
        #pragma unroll
        for (int c = 0; c < 4; ++c) Oacc[mh][c] = (f32x4_t){0.f, 0.f, 0.f, 0.f};
    float rowsum[2][4] = {{0.f, 0.f, 0.f, 0.f}, {0.f, 0.f, 0.f, 0.f}};

    for (int st = sa; st < sb; ++st) {
        const int s0 = st << 6;
        __syncthreads();   // previous tile's LDS readers done
        // stage K (8 rows per pass x 8)
        #pragma unroll
        for (int u = 0; u < 8; ++u) {
            int srow = krow + u * 8;
            f32x4_t kv = *(const f32x4_t*)&Kb[(s0 + srow) * (H_ * E_) + ke0];
            uint2 p;
            p.x = bpack(kv[1], kv[0]);
            p.y = bpack(kv[3], kv[2]);
            *(uint2*)&Ks[srow][ke0] = p;
        }
        // stage V^T (thread owns d=vd, 32 s values)
        float vv[32];
        #pragma unroll
        for (int j = 0; j < 32; ++j)
            vv[j] = Vb[(s0 + vsb * 32 + j) * (H_ * D_) + vd];
        #pragma unroll
        for (int u = 0; u < 8; ++u) {
            uint2 p;
            p.x = bpack(vv[u * 4 + 1], vv[u * 4 + 0]);
            p.y = bpack(vv[u * 4 + 3], vv[u * 4 + 2]);
            *(uint2*)&Vt[vd][vsb * 32 + u * 4] = p;
        }
        if (tid < 64) {
            int l_ = s0 + tid;
            moms[tid] = (l_ == 0) ? 0.f : fp[l_] - fp[l_ - 1];
        }
        __syncthreads();

        // S = Q K^T : B-frags shared across both mh row-blocks
        f32x4_t Sacc[2][4];
        #pragma unroll
        for (int mh = 0; mh < 2; ++mh)
            #pragma unroll
            for (int c = 0; c < 4; ++c) Sacc[mh][c] = (f32x4_t){0.f, 0.f, 0.f, 0.f};
        #pragma unroll
        for (int c = 0; c < 4; ++c) {
            bf16x8_t b_lo = *(const bf16x8_t*)&Ks[c * 16 + lrow][lgrp * 8];
            bf16x8_t b_hi = *(const bf16x8_t*)&Ks[c * 16 + lrow][32 + lgrp * 8];
            #pragma unroll
            for (int mh = 0; mh < 2; ++mh) {
                Sacc[mh][c] = __builtin_amdgcn_mfma_f32_16x16x32_bf16(aq[mh][0], b_lo, Sacc[mh][c], 0, 0, 0);
                Sacc[mh][c] = __builtin_amdgcn_mfma_f32_16x16x32_bf16(aq[mh][1], b_hi, Sacc[mh][c], 0, 0, 0);
            }
        }

        // P = exp2(S - ascale2*|dm|), mask on diagonal tile, store + rowsum
        unsigned short* Psw = &Ps[wave][0][0];
        #pragma unroll
        for (int c = 0; c < 4; ++c) {
            float ms = moms[c * 16 + lrow];
            int sg = s0 + c * 16 + lrow;
            #pragma unroll
            for (int mh = 0; mh < 2; ++mh) {
                #pragma unroll
                for (int r = 0; r < 4; ++r) {
                    float arg = Sacc[mh][c][r] - ascale2 * fabsf(mq[mh][r] - ms);
                    float e = __builtin_amdgcn_exp2f(arg);
                    if (st == qt && sg > qw0 + mh * 16 + lgrp * 4 + r) e = 0.f;
                    Psw[(mh * 16 + lgrp * 4 + r) * 68 + c * 16 + lrow] =
                        (unsigned short)(__float_as_uint(e) >> 16);
                    rowsum[mh][r] += e;
                }
            }
        }

        // O += P V : Vt frags shared across both mh row-blocks
        #pragma unroll
        for (int hh = 0; hh < 2; ++hh) {
            union { uint2 u2[2]; bf16x8_t v; } ap[2];
            #pragma unroll
            for (int mh = 0; mh < 2; ++mh) {
                ap[mh].u2[0] = *(const uint2*)&Psw[(mh * 16 + lrow) * 68 + hh * 32 + lgrp * 8];
                ap[mh].u2[1] = *(const uint2*)&Psw[(mh * 16 + lrow) * 68 + hh * 32 + lgrp * 8 + 4];
            }
            #pragma unroll
            for (int c2 = 0; c2 < 4; ++c2) {
                union { uint2 u2[2]; bf16x8_t v; } bb;
                bb.u2[0] = *(const uint2*)&Vt[c2 * 16 + lrow][hh * 32 + lgrp * 8];
                bb.u2[1] = *(const uint2*)&Vt[c2 * 16 + lrow][hh * 32 + lgrp * 8 + 4];
                #pragma unroll
                for (int mh = 0; mh < 2; ++mh)
                    Oacc[mh][c2] = __builtin_amdgcn_mfma_f32_16x16x32_bf16(ap[mh].v, bb.v, Oacc[mh][c2], 0, 0, 0);
            }
        }
    }

    // epilogue
    #pragma unroll
    for (int mh = 0; mh < 2; ++mh) {
        #pragma unroll
        for (int r = 0; r < 4; ++r) {
            float rs = rowsum[mh][r];
            rs += __shfl_xor(rs, 1);
            rs += __shfl_xor(rs, 2);
            rs += __shfl_xor(rs, 4);
            rs += __shfl_xor(rs, 8);
            if (!split) {
                float inv = 1.f / rs;
                size_t orow = ((bl + qw0 + mh * 16 + lgrp * 4 + r) * H_ + h) * D_;
                #pragma unroll
                for (int c = 0; c < 4; ++c)
                    out[orow + c * 16 + lrow] = Oacc[mh][c][r] * inv;
            } else {
                const int slot = (bh * 16 + (qt - 16)) * 2 + chunk;
                bf16_t* po = pO + (size_t)slot * 4096;
                float*  pr = prs + (size_t)slot * 64;
                int q = wave * 32 + mh * 16 + lgrp * 4 + r;
                if (lrow == 0) pr[q] = rs;
                #pragma unroll
                for (int c = 0; c < 4; ++c)
                    po[q * 64 + c * 16 + lrow] = to_bf16(Oacc[mh][c][r]);
            }
        }
    }
}

// ------- merge partials for qt in [16,31] ------------------------------------
__global__ __launch_bounds__(256) void merge_kernel(
        const bf16_t* __restrict__ pO, const float* __restrict__ prs,
        float* __restrict__ out) {
    const int bid = blockIdx.x;
    const int bh  = bid & 31;
    const int qt  = 16 + (bid >> 5);
    const int h   = bh & 15;
    const int b   = bh >> 4;
    const int t   = threadIdx.x;
    const int q   = t >> 2;
    const int d0  = (t & 3) << 4;

    const int slotA = (bh * 16 + (qt - 16)) * 2;
    const bf16_t* poA = pO + (size_t)slotA * 4096 + q * 64 + d0;
    const bf16_t* poB = poA + 4096;
    float rs = prs[slotA * 64 + q] + prs[(slotA + 1) * 64 + q];
    float inv = 1.f / rs;

    float* op = out + (((size_t)b * L_ + (qt << 6) + q) * H_ + h) * D_ + d0;
    #pragma unroll
    for (int i = 0; i < 16; i += 4) {
        f32x4_t o;
        #pragma unroll
        for (int k = 0; k < 4; ++k)
            o[k] = ((float)poA[i + k] + (float)poB[i + k]) * inv;
        *(f32x4_t*)&op[i] = o;
    }
}

extern "C" void kernel_launch(void* const* d_in, const int* in_sizes, int n_in,
                              void* d_out, int out_size, void* d_ws, size_t ws_size,
                              hipStream_t stream) {
    const float* Q     = (const float*)d_in[0];
    const float* K     = (const float*)d_in[1];
    const float* V     = (const float*)d_in[2];
    const float* raw   = (const float*)d_in[3];
    const float* w1    = (const float*)d_in[4];
    const float* b1    = (const float*)d_in[5];
    const float* w2    = (const float*)d_in[6];
    // d_in[7] = b2: cancels in the momentum diff, unused
    const float* alpha = (const float*)d_in[8];
    float* out = (float*)d_out;

    float* fused = (float*)d_ws;                        // 4096 f32
    bf16_t* w1t  = (bf16_t*)(fused + B_ * L_);          // 131072 bf16
    bf16_t* pO   = w1t + (size_t)DH_ * DM_;             // 1024*4096 bf16 (8 MB)
    float* prs   = (float*)(pO + (size_t)1024 * 4096);  // 1024*64 f32

    hipMemsetAsync(fused, 0, B_ * L_ * sizeof(float), stream);
    transpose_w1_kernel<<<32, 256, 0, stream>>>(w1, w1t);
    mlp_kernel<<<B_ * L_ / 16 * 2, 256, 0, stream>>>(raw, w1t, b1, w2, fused);
    attn_kernel<<<1536, 128, 0, stream>>>(Q, K, V, fused, alpha, out, pO, prs);
    merge_kernel<<<512, 256, 0, stream>>>(pO, prs, out);
}